// Round 1
// baseline (1336.359 us; speedup 1.0000x reference)
//
#include <hip/hip_runtime.h>
#include <math.h>

#define KK 25      // KS*KS
#define H1C 32
#define H2C 64
#define FCC 128
#define NCLS 10
#define NG 64

// ---------------- edge basis + degree ----------------
__global__ void edge_basis_kernel(const float* __restrict__ edge_attr,
                                  const int* __restrict__ edge_index, int E,
                                  int4* __restrict__ wi4, float4* __restrict__ b4,
                                  float* __restrict__ deg) {
    int e = blockIdx.x * blockDim.x + threadIdx.x;
    if (e >= E) return;
    float v0 = edge_attr[2 * e + 0] * 4.0f;
    float v1 = edge_attr[2 * e + 1] * 4.0f;
    int k0 = (int)floorf(v0); k0 = min(max(k0, 0), 3);
    int k1 = (int)floorf(v1); k1 = min(max(k1, 0), 3);
    float f0 = v0 - (float)k0, f1 = v1 - (float)k1;
    float g0 = 1.0f - f0, g1 = 1.0f - f1;
    // bits (bit_d0, bit_d1): (0,0),(0,1),(1,0),(1,1); wi = (k0+bit0) + 5*(k1+bit1)
    b4[e]  = make_float4(g0 * g1, g0 * f1, f0 * g1, f0 * f1);
    wi4[e] = make_int4(k0 + 5 * k1, k0 + 5 * (k1 + 1),
                       (k0 + 1) + 5 * k1, (k0 + 1) + 5 * (k1 + 1));
    int dst = edge_index[E + e];
    atomicAdd(&deg[dst], 1.0f);
}

__global__ void cnt_kernel(const int* __restrict__ batch, int N, float* __restrict__ cnt) {
    int n = blockIdx.x * blockDim.x + threadIdx.x;
    if (n < N) atomicAdd(&cnt[batch[n]], 1.0f);
}

// ---------------- layer 1: edge message + scatter (Cin=1) ----------------
__global__ void scatter1_kernel(const float* __restrict__ x,
                                const int* __restrict__ edge_index, int E,
                                const int4* __restrict__ wi4, const float4* __restrict__ b4,
                                const float* __restrict__ W1,  // [25,1,32]
                                float* __restrict__ agg1) {
    __shared__ float w1s[KK * H1C];
    for (int i = threadIdx.x; i < KK * H1C; i += blockDim.x) w1s[i] = W1[i];
    __syncthreads();
    int gid = blockIdx.x * blockDim.x + threadIdx.x;
    int e = gid >> 5, o = gid & 31;
    if (e >= E) return;
    int4 wi = wi4[e];
    float4 b = b4[e];
    float coef = b.x * w1s[wi.x * H1C + o] + b.y * w1s[wi.y * H1C + o] +
                 b.z * w1s[wi.z * H1C + o] + b.w * w1s[wi.w * H1C + o];
    int src = edge_index[e], dst = edge_index[E + e];
    atomicAdd(&agg1[dst * H1C + o], x[src] * coef);
}

__global__ void finalize1_kernel(const float* __restrict__ x,
                                 const float* __restrict__ agg1,
                                 const float* __restrict__ deg,
                                 const float* __restrict__ root1,  // [1,32]
                                 const float* __restrict__ b1,
                                 int N, float* __restrict__ h1) {
    int gid = blockIdx.x * blockDim.x + threadIdx.x;
    int n = gid >> 5, o = gid & 31;
    if (n >= N) return;
    float rdeg = 1.0f / fmaxf(deg[n], 1.0f);
    h1[gid] = fmaxf(agg1[gid] * rdeg + x[n] * root1[o] + b1[o], 0.0f);
}

// ---------------- layer 2: xW2[n, k*64+o] = sum_c h1[n,c] * W2[k,c,o] ----------------
__global__ void xw2_kernel(const float* __restrict__ h1,
                           const float* __restrict__ W2,  // [(k*32+c)*64+o]
                           int N, float* __restrict__ xW2) {
    __shared__ float hs[16][H1C];
    int node0 = blockIdx.x * 16;
    for (int i = threadIdx.x; i < 16 * H1C; i += blockDim.x) {
        int n = node0 + (i >> 5);
        hs[i >> 5][i & 31] = (n < N) ? h1[n * H1C + (i & 31)] : 0.0f;
    }
    __syncthreads();
    for (int out = threadIdx.x; out < KK * H2C; out += blockDim.x) {
        int k = out >> 6, o = out & 63;
        const float* w = W2 + k * (H1C * H2C) + o;
        float acc[16];
#pragma unroll
        for (int n = 0; n < 16; n++) acc[n] = 0.0f;
        for (int c = 0; c < H1C; c++) {
            float wv = w[c * H2C];
#pragma unroll
            for (int n = 0; n < 16; n++) acc[n] += hs[n][c] * wv;
        }
#pragma unroll
        for (int n = 0; n < 16; n++) {
            int node = node0 + n;
            if (node < N) xW2[(size_t)node * (KK * H2C) + out] = acc[n];
        }
    }
}

// ---------------- layer 2: edge gather + scatter ----------------
__global__ void scatter2_kernel(const int* __restrict__ edge_index, int E,
                                const int4* __restrict__ wi4, const float4* __restrict__ b4,
                                const float* __restrict__ xW2,
                                float* __restrict__ agg2) {
    int gid = blockIdx.x * blockDim.x + threadIdx.x;
    int e = gid >> 6, o = gid & 63;
    if (e >= E) return;
    int4 wi = wi4[e];
    float4 b = b4[e];
    int src = edge_index[e], dst = edge_index[E + e];
    const float* base = xW2 + (size_t)src * (KK * H2C);
    float msg = b.x * base[wi.x * H2C + o] + b.y * base[wi.y * H2C + o] +
                b.z * base[wi.z * H2C + o] + b.w * base[wi.w * H2C + o];
    atomicAdd(&agg2[dst * H2C + o], msg);
}

// ---------------- finalize layer 2 + fused mean-pool scatter ----------------
__global__ void finalize2_pool_kernel(const float* __restrict__ h1,
                                      const float* __restrict__ agg2,
                                      const float* __restrict__ deg,
                                      const float* __restrict__ root2,  // [32,64]
                                      const float* __restrict__ b2,
                                      const int* __restrict__ batch,
                                      int N, float* __restrict__ gsum) {
    int gid = blockIdx.x * blockDim.x + threadIdx.x;
    int n = gid >> 6, o = gid & 63;
    if (n >= N) return;
    float rdeg = 1.0f / fmaxf(deg[n], 1.0f);
    float acc = agg2[gid] * rdeg + b2[o];
    const float* hrow = h1 + n * H1C;
#pragma unroll
    for (int c = 0; c < H1C; c++) acc += hrow[c] * root2[c * H2C + o];
    float h2 = fmaxf(acc, 0.0f);
    atomicAdd(&gsum[batch[n] * H2C + o], h2);
}

// ---------------- head: mean, FC1+relu, FC2, log_softmax ----------------
__global__ void head_kernel(const float* __restrict__ gsum, const float* __restrict__ cnt,
                            const float* __restrict__ Wf1, const float* __restrict__ bf1,
                            const float* __restrict__ Wf2, const float* __restrict__ bf2,
                            float* __restrict__ out) {
    __shared__ float gc[H2C];
    __shared__ float t1[FCC];
    __shared__ float lg[NCLS];
    __shared__ float lse;
    int g = blockIdx.x, tid = threadIdx.x;
    if (tid < H2C) gc[tid] = gsum[g * H2C + tid] / fmaxf(cnt[g], 1.0f);
    __syncthreads();
    {
        float acc = bf1[tid];
        for (int c = 0; c < H2C; c++) acc += gc[c] * Wf1[c * FCC + tid];
        t1[tid] = fmaxf(acc, 0.0f);
    }
    __syncthreads();
    if (tid < NCLS) {
        float acc = bf2[tid];
        for (int j = 0; j < FCC; j++) acc += t1[j] * Wf2[j * NCLS + tid];
        lg[tid] = acc;
    }
    __syncthreads();
    if (tid == 0) {
        float m = lg[0];
        for (int c = 1; c < NCLS; c++) m = fmaxf(m, lg[c]);
        float s = 0.0f;
        for (int c = 0; c < NCLS; c++) s += expf(lg[c] - m);
        lse = m + logf(s);
    }
    __syncthreads();
    if (tid < NCLS) out[g * NCLS + tid] = lg[tid] - lse;
}

extern "C" void kernel_launch(void* const* d_in, const int* in_sizes, int n_in,
                              void* d_out, int out_size, void* d_ws, size_t ws_size,
                              hipStream_t stream) {
    const float* x          = (const float*)d_in[0];
    const float* edge_attr  = (const float*)d_in[1];
    const float* W1         = (const float*)d_in[2];
    const float* root1      = (const float*)d_in[3];
    const float* b1         = (const float*)d_in[4];
    const float* W2         = (const float*)d_in[5];
    const float* root2      = (const float*)d_in[6];
    const float* b2         = (const float*)d_in[7];
    const float* Wf1        = (const float*)d_in[8];
    const float* bf1        = (const float*)d_in[9];
    const float* Wf2        = (const float*)d_in[10];
    const float* bf2        = (const float*)d_in[11];
    const int*   edge_index = (const int*)d_in[12];
    const int*   batch      = (const int*)d_in[13];
    float* out = (float*)d_out;

    const int N = in_sizes[13];       // 20000
    const int E = in_sizes[12] / 2;   // 320000

    // workspace layout (floats). zero-block first for a single memset.
    float* ws   = (float*)d_ws;
    float* deg  = ws;                                  // N
    float* agg1 = deg + N;                             // N*H1C
    float* agg2 = agg1 + (size_t)N * H1C;              // N*H2C
    float* gsum = agg2 + (size_t)N * H2C;              // NG*H2C
    float* cnt  = gsum + NG * H2C;                     // NG
    size_t zero_floats = (size_t)N * (1 + H1C + H2C) + NG * H2C + NG;
    float* b4f  = cnt + NG;                            // E*4 (16B-aligned: offset %4==0)
    int*   wi4i = (int*)(b4f + (size_t)E * 4);         // E*4
    float* h1   = (float*)(wi4i + (size_t)E * 4);      // N*H1C
    float* xW2  = h1 + (size_t)N * H1C;                // N*KK*H2C  (~128 MB)

    hipMemsetAsync(deg, 0, zero_floats * sizeof(float), stream);

    edge_basis_kernel<<<(E + 255) / 256, 256, 0, stream>>>(
        edge_attr, edge_index, E, (int4*)wi4i, (float4*)b4f, deg);
    cnt_kernel<<<(N + 255) / 256, 256, 0, stream>>>(batch, N, cnt);

    scatter1_kernel<<<((size_t)E * 32 + 255) / 256, 256, 0, stream>>>(
        x, edge_index, E, (const int4*)wi4i, (const float4*)b4f, W1, agg1);
    finalize1_kernel<<<((size_t)N * 32 + 255) / 256, 256, 0, stream>>>(
        x, agg1, deg, root1, b1, N, h1);

    xw2_kernel<<<(N + 15) / 16, 256, 0, stream>>>(h1, W2, N, xW2);

    scatter2_kernel<<<((size_t)E * 64 + 255) / 256, 256, 0, stream>>>(
        edge_index, E, (const int4*)wi4i, (const float4*)b4f, xW2, agg2);
    finalize2_pool_kernel<<<((size_t)N * 64 + 255) / 256, 256, 0, stream>>>(
        h1, agg2, deg, root2, b2, batch, N, gsum);

    head_kernel<<<NG, FCC, 0, stream>>>(gsum, cnt, Wf1, bf1, Wf2, bf2, out);
}

// Round 2
// 492.946 us; speedup vs baseline: 2.7110x; 2.7110x over previous
//
#include <hip/hip_runtime.h>
#include <math.h>

#define KK 25      // KS*KS
#define H1C 32
#define H2C 64
#define FCC 128
#define NCLS 10
#define NG 64

// ---------------- edge basis + degree ----------------
__global__ void edge_basis_kernel(const float* __restrict__ edge_attr,
                                  const int* __restrict__ edge_index, int E,
                                  int4* __restrict__ wi4, float4* __restrict__ b4,
                                  float* __restrict__ deg) {
    int e = blockIdx.x * blockDim.x + threadIdx.x;
    if (e >= E) return;
    float v0 = edge_attr[2 * e + 0] * 4.0f;
    float v1 = edge_attr[2 * e + 1] * 4.0f;
    int k0 = (int)floorf(v0); k0 = min(max(k0, 0), 3);
    int k1 = (int)floorf(v1); k1 = min(max(k1, 0), 3);
    float f0 = v0 - (float)k0, f1 = v1 - (float)k1;
    float g0 = 1.0f - f0, g1 = 1.0f - f1;
    b4[e]  = make_float4(g0 * g1, g0 * f1, f0 * g1, f0 * f1);
    wi4[e] = make_int4(k0 + 5 * k1, k0 + 5 * (k1 + 1),
                       (k0 + 1) + 5 * k1, (k0 + 1) + 5 * (k1 + 1));
    int dst = edge_index[E + e];
    atomicAdd(&deg[dst], 1.0f);
}

__global__ void cnt_kernel(const int* __restrict__ batch, int N, float* __restrict__ cnt) {
    int n = blockIdx.x * blockDim.x + threadIdx.x;
    if (n < N) atomicAdd(&cnt[batch[n]], 1.0f);
}

// ---------------- layer 1: edge message + scatter (Cin=1) ----------------
__global__ void scatter1_kernel(const float* __restrict__ x,
                                const int* __restrict__ edge_index, int E,
                                const int4* __restrict__ wi4, const float4* __restrict__ b4,
                                const float* __restrict__ W1,  // [25,1,32]
                                float* __restrict__ agg1) {
    __shared__ float w1s[KK * H1C];
    for (int i = threadIdx.x; i < KK * H1C; i += blockDim.x) w1s[i] = W1[i];
    __syncthreads();
    int gid = blockIdx.x * blockDim.x + threadIdx.x;
    int e = gid >> 5, o = gid & 31;
    if (e >= E) return;
    int4 wi = wi4[e];
    float4 b = b4[e];
    float coef = b.x * w1s[wi.x * H1C + o] + b.y * w1s[wi.y * H1C + o] +
                 b.z * w1s[wi.z * H1C + o] + b.w * w1s[wi.w * H1C + o];
    int src = edge_index[e], dst = edge_index[E + e];
    atomicAdd(&agg1[dst * H1C + o], x[src] * coef);
}

__global__ void finalize1_kernel(const float* __restrict__ x,
                                 const float* __restrict__ agg1,
                                 const float* __restrict__ deg,
                                 const float* __restrict__ root1,  // [1,32]
                                 const float* __restrict__ b1,
                                 int N, float* __restrict__ h1) {
    int gid = blockIdx.x * blockDim.x + threadIdx.x;
    int n = gid >> 5, o = gid & 31;
    if (n >= N) return;
    float rdeg = 1.0f / fmaxf(deg[n], 1.0f);
    h1[gid] = fmaxf(agg1[gid] * rdeg + x[n] * root1[o] + b1[o], 0.0f);
}

// ---------------- layer 2 precompute: xW2 = h1 @ W2 (register-tiled GEMM) ----
// xW2[n, k*64+o] = sum_c h1[n,c] * W2[(k*32+c)*64+o]
// Block: 16 nodes, 256 threads. Thread owns (column-float4 jj, all 16 nodes).
// 400 float4-columns per row, covered in 2 strided passes (256 + 144).
// Stores: wave writes 64 lanes x 16B = 1KB contiguous, each address exactly once.
__global__ void xw2_kernel(const float* __restrict__ h1,
                           const float* __restrict__ W2,  // [(k*32+c)*64+o]
                           int N, float* __restrict__ xW2) {
    __shared__ float hs[16][H1C];
    int node0 = blockIdx.x * 16;
    for (int i = threadIdx.x; i < 16 * H1C; i += blockDim.x) {
        int n = node0 + (i >> 5);
        hs[i >> 5][i & 31] = (n < N) ? h1[n * H1C + (i & 31)] : 0.0f;
    }
    __syncthreads();
    int nvalid = min(16, N - node0);
    for (int jj = threadIdx.x; jj < KK * (H2C / 4); jj += blockDim.x) {
        int k = jj >> 4;               // jj / 16
        int o4 = (jj & 15) << 2;       // (jj%16)*4
        const float4* w = (const float4*)(W2 + k * (H1C * H2C) + o4);  // w[c*16]
        float4 acc[16];
#pragma unroll
        for (int n = 0; n < 16; n++) acc[n] = make_float4(0.f, 0.f, 0.f, 0.f);
#pragma unroll 4
        for (int c = 0; c < H1C; c++) {
            float4 wv = w[c * (H2C / 4)];
#pragma unroll
            for (int n = 0; n < 16; n++) {
                float h = hs[n][c];
                acc[n].x += h * wv.x; acc[n].y += h * wv.y;
                acc[n].z += h * wv.z; acc[n].w += h * wv.w;
            }
        }
        float4* outp = (float4*)xW2 + (size_t)node0 * (KK * H2C / 4) + jj;
        for (int n = 0; n < nvalid; n++) outp[(size_t)n * (KK * H2C / 4)] = acc[n];
    }
}

// ---------------- layer 2: edge gather + scatter ----------------
__global__ void scatter2_kernel(const int* __restrict__ edge_index, int E,
                                const int4* __restrict__ wi4, const float4* __restrict__ b4,
                                const float* __restrict__ xW2,
                                float* __restrict__ agg2) {
    int gid = blockIdx.x * blockDim.x + threadIdx.x;
    int e = gid >> 6, o = gid & 63;
    if (e >= E) return;
    int4 wi = wi4[e];
    float4 b = b4[e];
    int src = edge_index[e], dst = edge_index[E + e];
    const float* base = xW2 + (size_t)src * (KK * H2C);
    float msg = b.x * base[wi.x * H2C + o] + b.y * base[wi.y * H2C + o] +
                b.z * base[wi.z * H2C + o] + b.w * base[wi.w * H2C + o];
    atomicAdd(&agg2[dst * H2C + o], msg);
}

// ---------------- finalize layer 2 + fused mean-pool scatter ----------------
__global__ void finalize2_pool_kernel(const float* __restrict__ h1,
                                      const float* __restrict__ agg2,
                                      const float* __restrict__ deg,
                                      const float* __restrict__ root2,  // [32,64]
                                      const float* __restrict__ b2,
                                      const int* __restrict__ batch,
                                      int N, float* __restrict__ gsum) {
    int gid = blockIdx.x * blockDim.x + threadIdx.x;
    int n = gid >> 6, o = gid & 63;
    if (n >= N) return;
    float rdeg = 1.0f / fmaxf(deg[n], 1.0f);
    float acc = agg2[gid] * rdeg + b2[o];
    const float* hrow = h1 + n * H1C;
#pragma unroll
    for (int c = 0; c < H1C; c++) acc += hrow[c] * root2[c * H2C + o];
    float h2 = fmaxf(acc, 0.0f);
    atomicAdd(&gsum[batch[n] * H2C + o], h2);
}

// ---------------- head: mean, FC1+relu, FC2, log_softmax ----------------
__global__ void head_kernel(const float* __restrict__ gsum, const float* __restrict__ cnt,
                            const float* __restrict__ Wf1, const float* __restrict__ bf1,
                            const float* __restrict__ Wf2, const float* __restrict__ bf2,
                            float* __restrict__ out) {
    __shared__ float gc[H2C];
    __shared__ float t1[FCC];
    __shared__ float lg[NCLS];
    __shared__ float lse;
    int g = blockIdx.x, tid = threadIdx.x;
    if (tid < H2C) gc[tid] = gsum[g * H2C + tid] / fmaxf(cnt[g], 1.0f);
    __syncthreads();
    {
        float acc = bf1[tid];
        for (int c = 0; c < H2C; c++) acc += gc[c] * Wf1[c * FCC + tid];
        t1[tid] = fmaxf(acc, 0.0f);
    }
    __syncthreads();
    if (tid < NCLS) {
        float acc = bf2[tid];
        for (int j = 0; j < FCC; j++) acc += t1[j] * Wf2[j * NCLS + tid];
        lg[tid] = acc;
    }
    __syncthreads();
    if (tid == 0) {
        float m = lg[0];
        for (int c = 1; c < NCLS; c++) m = fmaxf(m, lg[c]);
        float s = 0.0f;
        for (int c = 0; c < NCLS; c++) s += expf(lg[c] - m);
        lse = m + logf(s);
    }
    __syncthreads();
    if (tid < NCLS) out[g * NCLS + tid] = lg[tid] - lse;
}

extern "C" void kernel_launch(void* const* d_in, const int* in_sizes, int n_in,
                              void* d_out, int out_size, void* d_ws, size_t ws_size,
                              hipStream_t stream) {
    const float* x          = (const float*)d_in[0];
    const float* edge_attr  = (const float*)d_in[1];
    const float* W1         = (const float*)d_in[2];
    const float* root1      = (const float*)d_in[3];
    const float* b1         = (const float*)d_in[4];
    const float* W2         = (const float*)d_in[5];
    const float* root2      = (const float*)d_in[6];
    const float* b2         = (const float*)d_in[7];
    const float* Wf1        = (const float*)d_in[8];
    const float* bf1        = (const float*)d_in[9];
    const float* Wf2        = (const float*)d_in[10];
    const float* bf2        = (const float*)d_in[11];
    const int*   edge_index = (const int*)d_in[12];
    const int*   batch      = (const int*)d_in[13];
    float* out = (float*)d_out;

    const int N = in_sizes[13];       // 20000
    const int E = in_sizes[12] / 2;   // 320000

    // workspace layout (floats). zero-block first for a single memset.
    float* ws   = (float*)d_ws;
    float* deg  = ws;                                  // N
    float* agg1 = deg + N;                             // N*H1C
    float* agg2 = agg1 + (size_t)N * H1C;              // N*H2C
    float* gsum = agg2 + (size_t)N * H2C;              // NG*H2C
    float* cnt  = gsum + NG * H2C;                     // NG
    size_t zero_floats = (size_t)N * (1 + H1C + H2C) + NG * H2C + NG;
    float* b4f  = cnt + NG;                            // E*4 (16B-aligned)
    int*   wi4i = (int*)(b4f + (size_t)E * 4);         // E*4
    float* h1   = (float*)(wi4i + (size_t)E * 4);      // N*H1C
    float* xW2  = h1 + (size_t)N * H1C;                // N*KK*H2C (~128 MB)

    hipMemsetAsync(deg, 0, zero_floats * sizeof(float), stream);

    edge_basis_kernel<<<(E + 255) / 256, 256, 0, stream>>>(
        edge_attr, edge_index, E, (int4*)wi4i, (float4*)b4f, deg);
    cnt_kernel<<<(N + 255) / 256, 256, 0, stream>>>(batch, N, cnt);

    scatter1_kernel<<<((size_t)E * 32 + 255) / 256, 256, 0, stream>>>(
        x, edge_index, E, (const int4*)wi4i, (const float4*)b4f, W1, agg1);
    finalize1_kernel<<<((size_t)N * 32 + 255) / 256, 256, 0, stream>>>(
        x, agg1, deg, root1, b1, N, h1);

    xw2_kernel<<<(N + 15) / 16, 256, 0, stream>>>(h1, W2, N, xW2);

    scatter2_kernel<<<((size_t)E * 64 + 255) / 256, 256, 0, stream>>>(
        edge_index, E, (const int4*)wi4i, (const float4*)b4f, xW2, agg2);
    finalize2_pool_kernel<<<((size_t)N * 64 + 255) / 256, 256, 0, stream>>>(
        h1, agg2, deg, root2, b2, batch, N, gsum);

    head_kernel<<<NG, FCC, 0, stream>>>(gsum, cnt, Wf1, bf1, Wf2, bf2, out);
}

// Round 3
// 409.764 us; speedup vs baseline: 3.2613x; 1.2030x over previous
//
#include <hip/hip_runtime.h>
#include <math.h>

#define KK 25      // KS*KS
#define H1C 32
#define H2C 64
#define FCC 128
#define NCLS 10
#define NG 64
#define M2 16      // nodes per block in l2_fused
#define SROW 804   // padded S row stride (800 + 4) to spread LDS banks

__device__ inline void fma4(float4& a, float s, const float4& w) {
    a.x = fmaf(s, w.x, a.x); a.y = fmaf(s, w.y, a.y);
    a.z = fmaf(s, w.z, a.z); a.w = fmaf(s, w.w, a.w);
}

// ---------------- edge basis + integer degree ----------------
__global__ void edge_basis_kernel(const float* __restrict__ edge_attr,
                                  const int* __restrict__ edge_index, int E,
                                  int4* __restrict__ wi4, float4* __restrict__ b4,
                                  int* __restrict__ degi) {
    int e = blockIdx.x * blockDim.x + threadIdx.x;
    if (e >= E) return;
    float v0 = edge_attr[2 * e + 0] * 4.0f;
    float v1 = edge_attr[2 * e + 1] * 4.0f;
    int k0 = (int)floorf(v0); k0 = min(max(k0, 0), 3);
    int k1 = (int)floorf(v1); k1 = min(max(k1, 0), 3);
    float f0 = v0 - (float)k0, f1 = v1 - (float)k1;
    float g0 = 1.0f - f0, g1 = 1.0f - f1;
    b4[e]  = make_float4(g0 * g1, g0 * f1, f0 * g1, f0 * f1);
    wi4[e] = make_int4(k0 + 5 * k1, k0 + 5 * (k1 + 1),
                       (k0 + 1) + 5 * k1, (k0 + 1) + 5 * (k1 + 1));
    atomicAdd(&degi[edge_index[E + e]], 1);
}

__global__ void cnt_kernel(const int* __restrict__ batch, int N, float* __restrict__ cnt) {
    int n = blockIdx.x * blockDim.x + threadIdx.x;
    if (n < N) atomicAdd(&cnt[batch[n]], 1.0f);
}

// ---------------- prefix-sum (3-kernel) over degi -> row_start ----------------
__global__ void scan1_kernel(const int* __restrict__ degi, int N,
                             int* __restrict__ incl, int* __restrict__ bsum) {
    __shared__ int s[256];
    int tid = threadIdx.x;
    int i = blockIdx.x * 256 + tid;
    int v = (i < N) ? degi[i] : 0;
    s[tid] = v;
    __syncthreads();
    for (int off = 1; off < 256; off <<= 1) {
        int t = (tid >= off) ? s[tid - off] : 0;
        __syncthreads();
        s[tid] += t;
        __syncthreads();
    }
    if (i < N) incl[i] = s[tid];
    if (tid == 255) bsum[blockIdx.x] = s[255];
}

__global__ void scan2_kernel(int* __restrict__ bsum, int nb) {
    __shared__ int s[256];
    int tid = threadIdx.x;
    int v = (tid < nb) ? bsum[tid] : 0;
    s[tid] = v;
    __syncthreads();
    for (int off = 1; off < 256; off <<= 1) {
        int t = (tid >= off) ? s[tid - off] : 0;
        __syncthreads();
        s[tid] += t;
        __syncthreads();
    }
    if (tid < nb) bsum[tid] = s[tid] - v;   // exclusive
}

__global__ void scan3_kernel(const int* __restrict__ incl, const int* __restrict__ degi,
                             const int* __restrict__ bsum, int N,
                             int* __restrict__ rowst, int* __restrict__ cur) {
    int i = blockIdx.x * 256 + threadIdx.x;
    if (i >= N) return;
    int r = incl[i] - degi[i] + bsum[blockIdx.x];
    rowst[i] = r;
    cur[i] = r;
}

// ---------------- bucket edges by dst (CSR) ----------------
__global__ void bucket_kernel(const int* __restrict__ edge_index, int E,
                              const int4* __restrict__ wi4, const float4* __restrict__ b4,
                              int* __restrict__ cur,
                              int* __restrict__ src_s, int4* __restrict__ wi4_s,
                              float4* __restrict__ b4_s) {
    int e = blockIdx.x * blockDim.x + threadIdx.x;
    if (e >= E) return;
    int dst = edge_index[E + e];
    int pos = atomicAdd(&cur[dst], 1);
    src_s[pos] = edge_index[e];
    wi4_s[pos] = wi4[e];
    b4_s[pos]  = b4[e];
}

// ---------------- layer 1 (CSR gather, fused finalize+relu) ----------------
// block 256 = 8 nodes x 32 lanes(o)
__global__ void l1_csr_kernel(const float* __restrict__ x,
                              const int* __restrict__ rowst, const int* __restrict__ degi,
                              const int* __restrict__ src_s, const int4* __restrict__ wi4_s,
                              const float4* __restrict__ b4_s,
                              const float* __restrict__ W1,   // [25*32]
                              const float* __restrict__ root1, const float* __restrict__ b1,
                              int N, float* __restrict__ h1) {
    __shared__ float w1s[KK * H1C];
    for (int i = threadIdx.x; i < KK * H1C; i += blockDim.x) w1s[i] = W1[i];
    __syncthreads();
    int n = blockIdx.x * 8 + (threadIdx.x >> 5);
    int o = threadIdx.x & 31;
    if (n >= N) return;
    int s0 = rowst[n], c = degi[n];
    float acc = 0.0f;
    for (int i = 0; i < c; i++) {
        int e = s0 + i;
        int4 wi = wi4_s[e];
        float4 b = b4_s[e];
        float xv = x[src_s[e]];
        float coef = b.x * w1s[wi.x * H1C + o] + b.y * w1s[wi.y * H1C + o] +
                     b.z * w1s[wi.z * H1C + o] + b.w * w1s[wi.w * H1C + o];
        acc = fmaf(xv, coef, acc);
    }
    float rdeg = 1.0f / fmaxf((float)c, 1.0f);
    h1[n * H1C + o] = fmaxf(acc * rdeg + x[n] * root1[o] + b1[o], 0.0f);
}

// ---------------- layer 2 fused: S-build (LDS) + S*W2 GEMM + root2 + relu + pool
// block 128 threads, M2=16 nodes. S[16][804] = 51.4 KB LDS.
__global__ __launch_bounds__(128) void l2_fused_kernel(
    const float* __restrict__ h1,
    const int* __restrict__ rowst, const int* __restrict__ degi,
    const int* __restrict__ src_s, const int4* __restrict__ wi4_s,
    const float4* __restrict__ b4_s,
    const float* __restrict__ W2,     // [(k*32+c)*64+o]
    const float* __restrict__ root2,  // [c*64+o]
    const float* __restrict__ b2,
    const int* __restrict__ batch,
    int N, float* __restrict__ gsum) {
    __shared__ float S[M2][SROW];
    int tid = threadIdx.x;
    int n0 = blockIdx.x * M2;
    for (int i = tid; i < M2 * SROW; i += 128) ((float*)S)[i] = 0.0f;
    __syncthreads();

    // ---- build: 4 groups x 32 lanes(c); group g owns local nodes [4g, 4g+4)
    {
        int g = tid >> 5, c = tid & 31;
        for (int sub = 0; sub < 4; sub++) {
            int ln = g * 4 + sub;
            int n = n0 + ln;
            if (n >= N) continue;
            int s0 = rowst[n], cnt = degi[n];
            for (int i = 0; i < cnt; i++) {
                int e = s0 + i;
                int src = src_s[e];
                int4 wi = wi4_s[e];
                float4 b = b4_s[e];
                float h = h1[src * H1C + c];
                S[ln][wi.x * H1C + c] += b.x * h;
                S[ln][wi.y * H1C + c] += b.y * h;
                S[ln][wi.z * H1C + c] += b.z * h;
                S[ln][wi.w * H1C + c] += b.w * h;
            }
        }
    }
    __syncthreads();

    // ---- GEMM: thread = (ngrp 0..7)x(o4 0..15); nodes na=2*ngrp, nb=na+1
    int ngrp = tid >> 4, o4 = tid & 15;
    int na = ngrp * 2, nb = na + 1;
    float4 accA = make_float4(0, 0, 0, 0), accB = make_float4(0, 0, 0, 0);
    for (int kc4 = 0; kc4 < (KK * H1C) / 4; kc4++) {
        float4 sA = *(const float4*)&S[na][kc4 * 4];
        float4 sB = *(const float4*)&S[nb][kc4 * 4];
        int kc = kc4 * 4;
        float4 w0 = *(const float4*)&W2[(kc + 0) * H2C + o4 * 4];
        float4 w1 = *(const float4*)&W2[(kc + 1) * H2C + o4 * 4];
        float4 w2 = *(const float4*)&W2[(kc + 2) * H2C + o4 * 4];
        float4 w3 = *(const float4*)&W2[(kc + 3) * H2C + o4 * 4];
        fma4(accA, sA.x, w0); fma4(accA, sA.y, w1); fma4(accA, sA.z, w2); fma4(accA, sA.w, w3);
        fma4(accB, sB.x, w0); fma4(accB, sB.y, w1); fma4(accB, sB.z, w2); fma4(accB, sB.w, w3);
    }

    // ---- epilogue: h2 = relu(acc/deg + h1@root2 + b2), into regs
    float4 hA = make_float4(0, 0, 0, 0), hB = make_float4(0, 0, 0, 0);
    {
        float4 bb = *(const float4*)&b2[o4 * 4];
        int nA = n0 + na, nB = n0 + nb;
        float rdA = 1.0f / fmaxf((float)((nA < N) ? degi[nA] : 0), 1.0f);
        float rdB = 1.0f / fmaxf((float)((nB < N) ? degi[nB] : 0), 1.0f);
        hA = make_float4(accA.x * rdA + bb.x, accA.y * rdA + bb.y,
                         accA.z * rdA + bb.z, accA.w * rdA + bb.w);
        hB = make_float4(accB.x * rdB + bb.x, accB.y * rdB + bb.y,
                         accB.z * rdB + bb.z, accB.w * rdB + bb.w);
        for (int c = 0; c < H1C; c++) {
            float4 rt = *(const float4*)&root2[c * H2C + o4 * 4];
            float hvA = (nA < N) ? h1[nA * H1C + c] : 0.0f;
            float hvB = (nB < N) ? h1[nB * H1C + c] : 0.0f;
            fma4(hA, hvA, rt);
            fma4(hB, hvB, rt);
        }
        hA.x = fmaxf(hA.x, 0.f); hA.y = fmaxf(hA.y, 0.f); hA.z = fmaxf(hA.z, 0.f); hA.w = fmaxf(hA.w, 0.f);
        hB.x = fmaxf(hB.x, 0.f); hB.y = fmaxf(hB.y, 0.f); hB.z = fmaxf(hB.z, 0.f); hB.w = fmaxf(hB.w, 0.f);
    }
    __syncthreads();                 // all GEMM reads of S done; reuse as h2 buffer
    float* h2buf = &S[0][0];         // [M2][64]
    *(float4*)&h2buf[na * H2C + o4 * 4] = hA;
    *(float4*)&h2buf[nb * H2C + o4 * 4] = hB;
    __syncthreads();

    // ---- pool: block-local reduction per graph, then one atomic per (graph,o)
    if (tid < H2C) {
        int o = tid;
        float run = 0.0f;
        int curg = batch[min(n0, N - 1)];
        for (int ln = 0; ln < M2; ln++) {
            int n = n0 + ln;
            if (n >= N) break;
            int g = batch[n];
            if (g != curg) {
                atomicAdd(&gsum[curg * H2C + o], run);
                run = 0.0f;
                curg = g;
            }
            run += h2buf[ln * H2C + o];
        }
        atomicAdd(&gsum[curg * H2C + o], run);
    }
}

// ---------------- head: mean, FC1+relu, FC2, log_softmax ----------------
__global__ void head_kernel(const float* __restrict__ gsum, const float* __restrict__ cnt,
                            const float* __restrict__ Wf1, const float* __restrict__ bf1,
                            const float* __restrict__ Wf2, const float* __restrict__ bf2,
                            float* __restrict__ out) {
    __shared__ float gc[H2C];
    __shared__ float t1[FCC];
    __shared__ float lg[NCLS];
    __shared__ float lse;
    int g = blockIdx.x, tid = threadIdx.x;
    if (tid < H2C) gc[tid] = gsum[g * H2C + tid] / fmaxf(cnt[g], 1.0f);
    __syncthreads();
    {
        float acc = bf1[tid];
        for (int c = 0; c < H2C; c++) acc += gc[c] * Wf1[c * FCC + tid];
        t1[tid] = fmaxf(acc, 0.0f);
    }
    __syncthreads();
    if (tid < NCLS) {
        float acc = bf2[tid];
        for (int j = 0; j < FCC; j++) acc += t1[j] * Wf2[j * NCLS + tid];
        lg[tid] = acc;
    }
    __syncthreads();
    if (tid == 0) {
        float m = lg[0];
        for (int c = 1; c < NCLS; c++) m = fmaxf(m, lg[c]);
        float s = 0.0f;
        for (int c = 0; c < NCLS; c++) s += expf(lg[c] - m);
        lse = m + logf(s);
    }
    __syncthreads();
    if (tid < NCLS) out[g * NCLS + tid] = lg[tid] - lse;
}

extern "C" void kernel_launch(void* const* d_in, const int* in_sizes, int n_in,
                              void* d_out, int out_size, void* d_ws, size_t ws_size,
                              hipStream_t stream) {
    const float* x          = (const float*)d_in[0];
    const float* edge_attr  = (const float*)d_in[1];
    const float* W1         = (const float*)d_in[2];
    const float* root1      = (const float*)d_in[3];
    const float* b1         = (const float*)d_in[4];
    const float* W2         = (const float*)d_in[5];
    const float* root2      = (const float*)d_in[6];
    const float* b2         = (const float*)d_in[7];
    const float* Wf1        = (const float*)d_in[8];
    const float* bf1        = (const float*)d_in[9];
    const float* Wf2        = (const float*)d_in[10];
    const float* bf2        = (const float*)d_in[11];
    const int*   edge_index = (const int*)d_in[12];
    const int*   batch      = (const int*)d_in[13];
    float* out = (float*)d_out;

    const int N = in_sizes[13];       // 20000
    const int E = in_sizes[12] / 2;   // 320000
    const int NB = (N + 255) / 256;   // scan blocks (79)

    // -------- workspace layout (16B-aligned vector arrays first) --------
    float* ws    = (float*)d_ws;
    float* b4f   = ws;                               // E*4 floats
    int*   wi4i  = (int*)(b4f + (size_t)4 * E);      // E*4
    float* b4s   = (float*)(wi4i + (size_t)4 * E);   // E*4 (sorted)
    int*   wi4s  = (int*)(b4s + (size_t)4 * E);      // E*4 (sorted)
    float* gsum  = (float*)(wi4s + (size_t)4 * E);   // NG*H2C  -- zero block
    float* cnt   = gsum + NG * H2C;                  // NG
    int*   degi  = (int*)(cnt + NG);                 // N       -- zero block end
    int*   rowst = degi + N;                         // N
    int*   cur   = rowst + N;                        // N
    int*   incl  = cur + N;                          // N
    int*   bsum  = incl + N;                         // 256
    int*   srcs  = bsum + 256;                       // E (sorted)
    float* h1    = (float*)(srcs + E);               // N*H1C

    size_t zero_elems = (size_t)NG * H2C + NG + N;
    hipMemsetAsync(gsum, 0, zero_elems * sizeof(float), stream);

    edge_basis_kernel<<<(E + 255) / 256, 256, 0, stream>>>(
        edge_attr, edge_index, E, (int4*)wi4i, (float4*)b4f, degi);
    cnt_kernel<<<NB, 256, 0, stream>>>(batch, N, cnt);

    scan1_kernel<<<NB, 256, 0, stream>>>(degi, N, incl, bsum);
    scan2_kernel<<<1, 256, 0, stream>>>(bsum, NB);
    scan3_kernel<<<NB, 256, 0, stream>>>(incl, degi, bsum, N, rowst, cur);

    bucket_kernel<<<(E + 255) / 256, 256, 0, stream>>>(
        edge_index, E, (const int4*)wi4i, (const float4*)b4f, cur,
        srcs, (int4*)wi4s, (float4*)b4s);

    l1_csr_kernel<<<(N + 7) / 8, 256, 0, stream>>>(
        x, rowst, degi, srcs, (const int4*)wi4s, (const float4*)b4s,
        W1, root1, b1, N, h1);

    l2_fused_kernel<<<(N + M2 - 1) / M2, 128, 0, stream>>>(
        h1, rowst, degi, srcs, (const int4*)wi4s, (const float4*)b4s,
        W2, root2, b2, batch, N, gsum);

    head_kernel<<<NG, FCC, 0, stream>>>(gsum, cnt, Wf1, bf1, Wf2, bf2, out);
}